// Round 2
// baseline (434.529 us; speedup 1.0000x reference)
//
#include <hip/hip_runtime.h>

// KernelNorm2d: B=16,C=64,H=W=256, k=2,s=2,pad=0.
// stride==kernel -> output[b,c,h,w] = (x[b,c,h,w]-mu)/sqrt(var+eps) where
// (mu,var) are over the 256 elements {c=0..63} x {2x2 spatial block}.
// fp32 in / fp32 out per the reference (jnp.float32).
//
// Block = (batch b, window-row i, 64-column chunk cc): 64ch x 2rows x 64cols
// = 32 KB held in registers (256 thr x 8 float4). 2 windows per thread.

#define CC 64
#define HH 256
#define WW 256

__global__ __launch_bounds__(256)
void knorm2d_kernel(const float* __restrict__ x, float* __restrict__ out) {
    const int t   = threadIdx.x;
    const int blk = blockIdx.x;
    const int b   = blk >> 9;      // 512 blocks per batch
    const int rem = blk & 511;
    const int i   = rem >> 2;      // window-row 0..127 (rows 2i, 2i+1)
    const int cc  = rem & 3;       // 64-col chunk 0..3
    const int vq  = t & 15;        // float4 slot within the 64-col chunk

    // element offset of (b, c=0, h=2i, w=64*cc + 4*vq)
    const size_t base = (size_t)b * (CC * HH * WW) + (size_t)(2 * i) * WW
                      + (size_t)(64 * cc + 4 * vq);

    float4 data[8];
    float sum[2] = {0.f, 0.f};
    float ssq[2] = {0.f, 0.f};

    #pragma unroll
    for (int k = 0; k < 8; ++k) {
        const int idx = k * 256 + t;
        const int seg = idx >> 4;          // 0..127 -> (c, hoff)
        const int c   = seg >> 1;
        const int hoff= seg & 1;
        const size_t off = base + (size_t)c * (HH * WW) + (size_t)hoff * WW;
        const float4 v = *reinterpret_cast<const float4*>(x + off);
        data[k] = v;
        sum[0] += v.x + v.y;   ssq[0] += v.x * v.x + v.y * v.y;
        sum[1] += v.z + v.w;   ssq[1] += v.z * v.z + v.w * v.w;
    }

    // Threads sharing vq: t = u*16+vq, u=0..15. Wave w holds u=4w..4w+3 at
    // lanes vq, vq+16, vq+32, vq+48 -> butterfly over 16 and 32.
    #pragma unroll
    for (int q = 0; q < 2; ++q) {
        sum[q] += __shfl_xor(sum[q], 16);
        ssq[q] += __shfl_xor(ssq[q], 16);
        sum[q] += __shfl_xor(sum[q], 32);
        ssq[q] += __shfl_xor(ssq[q], 32);
    }

    __shared__ float part[4][16][4];   // [wave][vq][{s0,q0,s1,q1}]
    __shared__ float stats[32][2];     // [window-in-block][{mu, rsig}]

    const int wave = t >> 6;
    const int lid  = t & 63;
    if (lid < 16) {
        part[wave][lid][0] = sum[0];
        part[wave][lid][1] = ssq[0];
        part[wave][lid][2] = sum[1];
        part[wave][lid][3] = ssq[1];
    }
    __syncthreads();

    if (t < 32) {                       // window win = t = 2*vq + q
        const int v = t >> 1;
        const int q = t & 1;
        float s = 0.f, s2 = 0.f;
        #pragma unroll
        for (int w = 0; w < 4; ++w) {
            s  += part[w][v][2 * q];
            s2 += part[w][v][2 * q + 1];
        }
        const float mu  = s  * (1.0f / 256.0f);
        const float var = s2 * (1.0f / 256.0f) - mu * mu;
        stats[t][0] = mu;
        stats[t][1] = rsqrtf(var + 1e-5f);
    }
    __syncthreads();

    const float mu0 = stats[2 * vq][0],     rs0 = stats[2 * vq][1];
    const float mu1 = stats[2 * vq + 1][0], rs1 = stats[2 * vq + 1][1];

    #pragma unroll
    for (int k = 0; k < 8; ++k) {
        const int idx = k * 256 + t;
        const int seg = idx >> 4;
        const int c   = seg >> 1;
        const int hoff= seg & 1;
        const size_t off = base + (size_t)c * (HH * WW) + (size_t)hoff * WW;
        float4 v = data[k];
        float4 o;
        o.x = (v.x - mu0) * rs0;
        o.y = (v.y - mu0) * rs0;
        o.z = (v.z - mu1) * rs1;
        o.w = (v.w - mu1) * rs1;
        *reinterpret_cast<float4*>(out + off) = o;
    }
}

extern "C" void kernel_launch(void* const* d_in, const int* in_sizes, int n_in,
                              void* d_out, int out_size, void* d_ws, size_t ws_size,
                              hipStream_t stream) {
    const float* x = (const float*)d_in[0];
    float* out     = (float*)d_out;
    // 16 batches * 128 window-rows * 4 column-chunks = 8192 blocks
    knorm2d_kernel<<<dim3(8192), dim3(256), 0, stream>>>(x, out);
}